// Round 1
// baseline (1111.425 us; speedup 1.0000x reference)
//
#include <hip/hip_runtime.h>
#include <stdint.h>

typedef unsigned short u16;
typedef short short8 __attribute__((ext_vector_type(8)));   // 8 bf16 for MFMA A/B
typedef float f32x4 __attribute__((ext_vector_type(4)));    // MFMA C/D
typedef u16 u16x8 __attribute__((ext_vector_type(8)));

#define DIMN 1536
#define LQ   6400
#define LKV  3200
#define NHEAD 12
#define HDIM  128

__device__ __forceinline__ u16 f2bf(float f) {              // RNE fp32->bf16
  uint32_t u = __builtin_bit_cast(uint32_t, f);
  u += 0x7fffu + ((u >> 16) & 1u);
  return (u16)(u >> 16);
}
__device__ __forceinline__ float bf2f(u16 h) {
  uint32_t u = ((uint32_t)h) << 16;
  return __builtin_bit_cast(float, u);
}
__device__ __forceinline__ void async16(const void* g, void* l) {
  __builtin_amdgcn_global_load_lds((const __attribute__((address_space(1))) void*)g,
                                   (__attribute__((address_space(3))) void*)l, 16, 0, 0);
}
#define MFMA16(a, b, c) __builtin_amdgcn_mfma_f32_16x16x32_bf16((a), (b), (c), 0, 0, 0)

// ---------------- K0a: x fp32 -> bf16 ----------------
__global__ void __launch_bounds__(256) convert_x(const float* __restrict__ x, u16* __restrict__ xb) {
  size_t i = ((size_t)blockIdx.x * 256 + threadIdx.x) * 4;
  float4 v = *(const float4*)(x + i);
  union { u16 h[4]; uint2 u; } p;
  p.h[0] = f2bf(v.x); p.h[1] = f2bf(v.y); p.h[2] = f2bf(v.z); p.h[3] = f2bf(v.w);
  *(uint2*)(xb + i) = p.u;
}

// ---------------- K0b: W fp32 -> bf16 transposed (Wt[n][k]) ----------------
__global__ void __launch_bounds__(256) transpose_w(const float* __restrict__ Wq, const float* __restrict__ Wk,
                                                   const float* __restrict__ Wv, const float* __restrict__ Wo,
                                                   u16* __restrict__ wt) {
  int z = blockIdx.z;
  const float* W = (z == 0) ? Wq : (z == 1) ? Wk : (z == 2) ? Wv : Wo;
  u16* dst = wt + (size_t)z * DIMN * DIMN;
  __shared__ float tile[64][65];
  int c0 = blockIdx.x * 64, r0 = blockIdx.y * 64;
  int t = threadIdx.x;
  int rr = t >> 4, cc = (t & 15) * 4;
#pragma unroll
  for (int j = 0; j < 4; j++) {
    float4 v = *(const float4*)(W + (size_t)(r0 + rr + j * 16) * DIMN + c0 + cc);
    tile[rr + j * 16][cc + 0] = v.x; tile[rr + j * 16][cc + 1] = v.y;
    tile[rr + j * 16][cc + 2] = v.z; tile[rr + j * 16][cc + 3] = v.w;
  }
  __syncthreads();
  int nn = t >> 2, kk = (t & 3) * 16;
  u16x8 a, b;
#pragma unroll
  for (int q = 0; q < 8; q++) a[q] = f2bf(tile[kk + q][nn]);
#pragma unroll
  for (int q = 0; q < 8; q++) b[q] = f2bf(tile[kk + 8 + q][nn]);
  u16* o = dst + (size_t)(c0 + nn) * DIMN + r0 + kk;
  *(u16x8*)(o) = a;
  *(u16x8*)(o + 8) = b;
}

// ---------------- shared GEMM mainloop: C(128x128) = A[m][k] * Wt[n][k]^T ----------------
__device__ __forceinline__ void gemm_tile(const u16* __restrict__ A, const u16* __restrict__ Bt,
                                          int m0, int n0, u16* sA, u16* sB, f32x4 acc[4][4]) {
  const int tid = threadIdx.x;
  const int wid = tid >> 6, lane = tid & 63;
  const int wm = wid >> 1, wn = wid & 1;
  const int l15 = lane & 15, quad = lane >> 4;
#pragma unroll
  for (int i = 0; i < 4; i++)
#pragma unroll
    for (int j = 0; j < 4; j++) acc[i][j] = f32x4{0.f, 0.f, 0.f, 0.f};
  const u16* ga = A  + (size_t)(m0 + wid * 32 + (lane >> 3)) * DIMN + (lane & 7) * 8;
  const u16* gb = Bt + (size_t)(n0 + wid * 32 + (lane >> 3)) * DIMN + (lane & 7) * 8;
  u16* la = sA + (wid * 32) * 64;
  u16* lb = sB + (wid * 32) * 64;
  for (int k0 = 0; k0 < DIMN; k0 += 64) {
    __syncthreads();
#pragma unroll
    for (int j = 0; j < 4; j++) async16(ga + k0 + j * 8 * DIMN, la + j * 8 * 64);
#pragma unroll
    for (int j = 0; j < 4; j++) async16(gb + k0 + j * 8 * DIMN, lb + j * 8 * 64);
    __syncthreads();
#pragma unroll
    for (int kk = 0; kk < 64; kk += 32) {
      short8 af[4], bf[4];
#pragma unroll
      for (int s = 0; s < 4; s++) af[s] = *(const short8*)(sA + (wm * 64 + s * 16 + l15) * 64 + kk + quad * 8);
#pragma unroll
      for (int s = 0; s < 4; s++) bf[s] = *(const short8*)(sB + (wn * 64 + s * 16 + l15) * 64 + kk + quad * 8);
#pragma unroll
      for (int i = 0; i < 4; i++)
#pragma unroll
        for (int j = 0; j < 4; j++) acc[i][j] = MFMA16(af[i], bf[j], acc[i][j]);
    }
  }
}

// ---------------- K1: QKV projection GEMM + bias, head-major stores, k/v subsample, v transposed ----------------
__global__ void __launch_bounds__(256) gemm_qkv(const u16* __restrict__ xb, const u16* __restrict__ wt,
                                                const float* __restrict__ bq, const float* __restrict__ bk,
                                                const float* __restrict__ bv,
                                                u16* __restrict__ qb, u16* __restrict__ kb, u16* __restrict__ vtb) {
  __shared__ u16 sA[128 * 64];
  __shared__ u16 sB[128 * 64];
  int z = blockIdx.z;
  const u16* Bt = wt + (size_t)z * DIMN * DIMN;
  int m0 = blockIdx.x * 128, n0 = blockIdx.y * 128;
  f32x4 acc[4][4];
  gemm_tile(xb, Bt, m0, n0, sA, sB, acc);
  const float* bias = (z == 0) ? bq : (z == 1) ? bk : bv;
  int tid = threadIdx.x, wid = tid >> 6, lane = tid & 63;
  int wm = wid >> 1, wn = wid & 1, l15 = lane & 15, quad = lane >> 4;
#pragma unroll
  for (int sn = 0; sn < 4; sn++) {
    int c = n0 + wn * 64 + sn * 16 + l15;
    float bb = bias[c];
    int h = c >> 7, d = c & 127;
#pragma unroll
    for (int sm = 0; sm < 4; sm++) {
      int rl = wm * 64 + sm * 16 + quad * 4;
#pragma unroll
      for (int r = 0; r < 4; r++) {
        float val = acc[sm][sn][r] + bb;
        int row = m0 + rl + r;
        if (z == 0) {
          qb[((size_t)h * LQ + row) * HDIM + d] = f2bf(val);
        } else if ((rl + r) < 64) {                 // kept tokens: l&64==0
          int lk = (row >> 7) * 64 + (row & 63);
          if (z == 1) kb[((size_t)h * LKV + lk) * HDIM + d] = f2bf(val);
          else        vtb[((size_t)h * HDIM + d) * LKV + lk] = f2bf(val);
        }
      }
    }
  }
}

// ---------------- K2: in-place RMSNorm + gain + RoPE on q (6400 tok) and k (3200 tok) ----------------
__global__ void __launch_bounds__(256) rms_rope(u16* __restrict__ qb, u16* __restrict__ kb,
                                                const float* __restrict__ freqs,
                                                const float* __restrict__ gq, const float* __restrict__ gk) {
  int t = blockIdx.x * 4 + (threadIdx.x >> 6);   // token slot 0..9599
  int lane = threadIdx.x & 63;
  bool isQ = t < LQ;
  int tok = isQ ? t : t - LQ;
  int Lt = isQ ? LQ : LKV;
  u16* buf = isQ ? qb : kb;
  const float* g = isQ ? gq : gk;
  int l = isQ ? tok : ((tok >> 6) * 128 + (tok & 63));   // original token index for RoPE angles
  float a[12], b[12];
  float ss = 0.f;
#pragma unroll
  for (int n = 0; n < NHEAD; n++) {
    ushort2 p = *(const ushort2*)(buf + ((size_t)n * Lt + tok) * HDIM + 2 * lane);
    a[n] = bf2f(p.x); b[n] = bf2f(p.y);
    ss += a[n] * a[n] + b[n] * b[n];
  }
#pragma unroll
  for (int off = 32; off; off >>= 1) ss += __shfl_xor(ss, off);
  float rs = rsqrtf(ss * (1.0f / 1536.0f) + 1e-6f);
  int i = lane;                                   // RoPE pair index 0..63
  int fi = (i < 22) ? (l >> 6) : (i < 43) ? ((l >> 3) & 7) : (l & 7);
  float ang = freqs[fi * 64 + i];
  float sn, cs;
  sincosf(ang, &sn, &cs);
#pragma unroll
  for (int n = 0; n < NHEAD; n++) {
    float2 gg = *(const float2*)(g + n * HDIM + 2 * lane);
    float xr = a[n] * rs * gg.x;
    float xi = b[n] * rs * gg.y;
    ushort2 o;
    o.x = f2bf(xr * cs - xi * sn);
    o.y = f2bf(xr * sn + xi * cs);
    *(ushort2*)(buf + ((size_t)n * Lt + tok) * HDIM + 2 * lane) = o;
  }
}

// ---------------- K3: flash attention, BM=128 (8 waves x 16 rows), BN=128, online softmax ----------------
__global__ void __launch_bounds__(512) attn(const u16* __restrict__ qb, const u16* __restrict__ kb,
                                            const u16* __restrict__ vtb, u16* __restrict__ ob) {
  __shared__ u16 Ks[128 * 128];       // [key_local][d]
  __shared__ u16 Vs[128 * 128];       // [d][key_local]  (V transposed)
  __shared__ u16 Ps[8 * 16 * 128];    // per-wave P tile [row][key]
  // XCD swizzle: keep each XCD's K/V working set <= 2 heads (fits 4MB L2)
  int x8 = blockIdx.x & 7, gsl = blockIdx.x >> 3;
  int w = x8 * 75 + gsl;              // 600 = 8*75
  int h = w / 50, qt = w % 50;
  int tid = threadIdx.x, wid = tid >> 6, lane = tid & 63;
  int l15 = lane & 15, quad = lane >> 4;
  int l0 = qt * 128;
  short8 qf[4];
  const u16* qrow = qb + ((size_t)h * LQ + l0 + wid * 16 + l15) * HDIM;
#pragma unroll
  for (int ks = 0; ks < 4; ks++) qf[ks] = *(const short8*)(qrow + ks * 32 + quad * 8);
  f32x4 O[8];
#pragma unroll
  for (int d = 0; d < 8; d++) O[d] = f32x4{0.f, 0.f, 0.f, 0.f};
  float m_[4] = {-3e38f, -3e38f, -3e38f, -3e38f};
  float l_[4] = {0.f, 0.f, 0.f, 0.f};
  const float scale = 0.08838834764831845f;   // 1/sqrt(128)
  const u16* kg = kb + (size_t)h * LKV * HDIM;
  const u16* vg = vtb + (size_t)h * HDIM * LKV;
  u16* PsW = Ps + wid * 16 * 128;
  for (int kb0 = 0; kb0 < LKV; kb0 += 128) {
    __syncthreads();
#pragma unroll
    for (int j = 0; j < 4; j++)
      async16(kg + (size_t)(kb0 + wid * 16 + j * 4 + quad) * HDIM + l15 * 8, Ks + (wid * 16 + j * 4) * 128);
#pragma unroll
    for (int j = 0; j < 4; j++)
      async16(vg + (size_t)(wid * 16 + j * 4 + quad) * LKV + kb0 + l15 * 8, Vs + (wid * 16 + j * 4) * 128);
    __syncthreads();
    // S = Q*K^T  (rows = wave's 16 q rows, cols = 128 keys)
    f32x4 S[8];
#pragma unroll
    for (int nt = 0; nt < 8; nt++) {
      S[nt] = f32x4{0.f, 0.f, 0.f, 0.f};
#pragma unroll
      for (int ks = 0; ks < 4; ks++) {
        short8 kf = *(const short8*)(Ks + (nt * 16 + l15) * 128 + ks * 32 + quad * 8);
        S[nt] = MFMA16(qf[ks], kf, S[nt]);
      }
    }
    // online softmax (rows live on quad: row = quad*4+r, replicated over 16 lanes)
    float al[4];
#pragma unroll
    for (int r = 0; r < 4; r++) {
      float mx = S[0][r];
#pragma unroll
      for (int nt = 1; nt < 8; nt++) mx = fmaxf(mx, S[nt][r]);
#pragma unroll
      for (int off = 1; off < 16; off <<= 1) mx = fmaxf(mx, __shfl_xor(mx, off));
      float mn = fmaxf(m_[r], mx);
      al[r] = __expf((m_[r] - mn) * scale);
      m_[r] = mn;
      float sum = 0.f;
#pragma unroll
      for (int nt = 0; nt < 8; nt++) {
        float p = __expf((S[nt][r] - mn) * scale);
        S[nt][r] = p;
        sum += p;
      }
#pragma unroll
      for (int off = 1; off < 16; off <<= 1) sum += __shfl_xor(sum, off);
      l_[r] = l_[r] * al[r] + sum;
    }
    // P (C-layout) -> LDS -> A-layout
#pragma unroll
    for (int nt = 0; nt < 8; nt++)
#pragma unroll
      for (int r = 0; r < 4; r++)
        PsW[(quad * 4 + r) * 128 + nt * 16 + l15] = f2bf(S[nt][r]);
#pragma unroll
    for (int d = 0; d < 8; d++) {
      f32x4 o = O[d];
#pragma unroll
      for (int r = 0; r < 4; r++) o[r] *= al[r];
      O[d] = o;
    }
    // O += P * V
#pragma unroll
    for (int ks = 0; ks < 4; ks++) {
      short8 pf = *(const short8*)(PsW + l15 * 128 + ks * 32 + quad * 8);
#pragma unroll
      for (int d = 0; d < 8; d++) {
        short8 vf = *(const short8*)(Vs + (d * 16 + l15) * 128 + ks * 32 + quad * 8);
        O[d] = MFMA16(pf, vf, O[d]);
      }
    }
  }
  float inv[4];
#pragma unroll
  for (int r = 0; r < 4; r++) inv[r] = 1.0f / l_[r];
#pragma unroll
  for (int d = 0; d < 8; d++)
#pragma unroll
    for (int r = 0; r < 4; r++) {
      int row = l0 + wid * 16 + quad * 4 + r;
      int col = h * HDIM + d * 16 + l15;
      ob[(size_t)row * DIMN + col] = f2bf(O[d][r] * inv[r]);
    }
}

// ---------------- K4: output projection GEMM + bias -> fp32 ----------------
__global__ void __launch_bounds__(256) gemm_out(const u16* __restrict__ ob, const u16* __restrict__ wto,
                                                const float* __restrict__ bo, float* __restrict__ out) {
  __shared__ u16 sA[128 * 64];
  __shared__ u16 sB[128 * 64];
  int m0 = blockIdx.x * 128, n0 = blockIdx.y * 128;
  f32x4 acc[4][4];
  gemm_tile(ob, wto, m0, n0, sA, sB, acc);
  int tid = threadIdx.x, wid = tid >> 6, lane = tid & 63;
  int wm = wid >> 1, wn = wid & 1, l15 = lane & 15, quad = lane >> 4;
#pragma unroll
  for (int sn = 0; sn < 4; sn++) {
    int c = n0 + wn * 64 + sn * 16 + l15;
    float bb = bo[c];
#pragma unroll
    for (int sm = 0; sm < 4; sm++) {
      int rl = wm * 64 + sm * 16 + quad * 4;
#pragma unroll
      for (int r = 0; r < 4; r++)
        out[(size_t)(m0 + rl + r) * DIMN + c] = acc[sm][sn][r] + bb;
    }
  }
}

extern "C" void kernel_launch(void* const* d_in, const int* in_sizes, int n_in,
                              void* d_out, int out_size, void* d_ws, size_t ws_size,
                              hipStream_t stream) {
  (void)in_sizes; (void)n_in; (void)out_size; (void)ws_size;
  const float* x     = (const float*)d_in[0];
  const float* freqs = (const float*)d_in[1];
  const float* Wq    = (const float*)d_in[2];
  const float* bq    = (const float*)d_in[3];
  const float* Wk    = (const float*)d_in[4];
  const float* bk    = (const float*)d_in[5];
  const float* Wv    = (const float*)d_in[6];
  const float* bv    = (const float*)d_in[7];
  const float* Wo    = (const float*)d_in[8];
  const float* bo    = (const float*)d_in[9];
  const float* gq    = (const float*)d_in[10];
  const float* gk    = (const float*)d_in[11];

  u16* xb  = (u16*)d_ws;                                   // [6400][1536]
  u16* wt  = xb  + (size_t)LQ * DIMN;                      // [4][1536][1536] transposed bf16 weights
  u16* qb  = wt  + (size_t)4 * DIMN * DIMN;                // [12][6400][128]
  u16* kb  = qb  + (size_t)NHEAD * LQ * HDIM;              // [12][3200][128]
  u16* vtb = kb  + (size_t)NHEAD * LKV * HDIM;             // [12][128][3200]
  u16* ob  = vtb + (size_t)NHEAD * HDIM * LKV;             // [6400][1536]

  convert_x<<<dim3(9600), dim3(256), 0, stream>>>(x, xb);
  transpose_w<<<dim3(24, 24, 4), dim3(256), 0, stream>>>(Wq, Wk, Wv, Wo, wt);
  gemm_qkv<<<dim3(50, 12, 3), dim3(256), 0, stream>>>(xb, wt, bq, bk, bv, qb, kb, vtb);
  rms_rope<<<dim3(2400), dim3(256), 0, stream>>>(qb, kb, freqs, gq, gk);
  attn<<<dim3(600), dim3(512), 0, stream>>>(qb, kb, vtb, ob);
  gemm_out<<<dim3(50, 12), dim3(256), 0, stream>>>(ob, wt + (size_t)3 * DIMN * DIMN, bo, (float*)d_out);
}

// Round 2
// 788.329 us; speedup vs baseline: 1.4098x; 1.4098x over previous
//
#include <hip/hip_runtime.h>
#include <stdint.h>

typedef unsigned short u16;
typedef short short8 __attribute__((ext_vector_type(8)));   // 8 bf16 for MFMA A/B
typedef float f32x4 __attribute__((ext_vector_type(4)));    // MFMA C/D
typedef u16 u16x8 __attribute__((ext_vector_type(8)));

#define DIMN 1536
#define LQ   6400
#define LKV  3200
#define NHEAD 12
#define HDIM  128

__device__ __forceinline__ u16 f2bf(float f) {              // RNE fp32->bf16
  uint32_t u = __builtin_bit_cast(uint32_t, f);
  u += 0x7fffu + ((u >> 16) & 1u);
  return (u16)(u >> 16);
}
__device__ __forceinline__ float bf2f(u16 h) {
  uint32_t u = ((uint32_t)h) << 16;
  return __builtin_bit_cast(float, u);
}
__device__ __forceinline__ void async16(const void* g, void* l) {
  __builtin_amdgcn_global_load_lds((const __attribute__((address_space(1))) void*)g,
                                   (__attribute__((address_space(3))) void*)l, 16, 0, 0);
}
#define MFMA16(a, b, c) __builtin_amdgcn_mfma_f32_16x16x32_bf16((a), (b), (c), 0, 0, 0)

// ---------------- K0a: x fp32 -> bf16 ----------------
__global__ void __launch_bounds__(256) convert_x(const float* __restrict__ x, u16* __restrict__ xb) {
  size_t i = ((size_t)blockIdx.x * 256 + threadIdx.x) * 4;
  float4 v = *(const float4*)(x + i);
  union { u16 h[4]; uint2 u; } p;
  p.h[0] = f2bf(v.x); p.h[1] = f2bf(v.y); p.h[2] = f2bf(v.z); p.h[3] = f2bf(v.w);
  *(uint2*)(xb + i) = p.u;
}

// ---------------- K0b: W fp32 -> bf16 transposed (Wt[n][k]) ----------------
__global__ void __launch_bounds__(256) transpose_w(const float* __restrict__ Wq, const float* __restrict__ Wk,
                                                   const float* __restrict__ Wv, const float* __restrict__ Wo,
                                                   u16* __restrict__ wt) {
  int z = blockIdx.z;
  const float* W = (z == 0) ? Wq : (z == 1) ? Wk : (z == 2) ? Wv : Wo;
  u16* dst = wt + (size_t)z * DIMN * DIMN;
  __shared__ float tile[64][65];
  int c0 = blockIdx.x * 64, r0 = blockIdx.y * 64;
  int t = threadIdx.x;
  int rr = t >> 4, cc = (t & 15) * 4;
#pragma unroll
  for (int j = 0; j < 4; j++) {
    float4 v = *(const float4*)(W + (size_t)(r0 + rr + j * 16) * DIMN + c0 + cc);
    tile[rr + j * 16][cc + 0] = v.x; tile[rr + j * 16][cc + 1] = v.y;
    tile[rr + j * 16][cc + 2] = v.z; tile[rr + j * 16][cc + 3] = v.w;
  }
  __syncthreads();
  int nn = t >> 2, kk = (t & 3) * 16;
  u16x8 a, b;
#pragma unroll
  for (int q = 0; q < 8; q++) a[q] = f2bf(tile[kk + q][nn]);
#pragma unroll
  for (int q = 0; q < 8; q++) b[q] = f2bf(tile[kk + 8 + q][nn]);
  u16* o = dst + (size_t)(c0 + nn) * DIMN + r0 + kk;
  *(u16x8*)(o) = a;
  *(u16x8*)(o + 8) = b;
}

// ---------------- shared GEMM mainloop: C(128x128) = A[m][k] * Wt[n][k]^T ----------------
// LDS tiles [128 rows][64 k] with XOR swizzle: element (row, k) stored at group (k>>3)^(row&7).
// Staging keeps lane->LDS fixed (global_load_lds) and swizzles the global source column instead.
__device__ __forceinline__ void gemm_tile(const u16* __restrict__ A, const u16* __restrict__ Bt,
                                          int m0, int n0, u16* sA, u16* sB, f32x4 acc[4][4]) {
  const int tid = threadIdx.x;
  const int wid = tid >> 6, lane = tid & 63;
  const int wm = wid >> 1, wn = wid & 1;
  const int l15 = lane & 15, quad = lane >> 4;
  const int lrow = lane >> 3;           // row within 8-row staging slab
  const int sgrp = (lane & 7) ^ lrow;   // swizzled source column group
#pragma unroll
  for (int i = 0; i < 4; i++)
#pragma unroll
    for (int j = 0; j < 4; j++) acc[i][j] = f32x4{0.f, 0.f, 0.f, 0.f};
  const u16* ga = A  + (size_t)(m0 + wid * 32 + lrow) * DIMN + sgrp * 8;
  const u16* gb = Bt + (size_t)(n0 + wid * 32 + lrow) * DIMN + sgrp * 8;
  u16* la = sA + (wid * 32) * 64;
  u16* lb = sB + (wid * 32) * 64;
  const int swz = l15 & 7;
  for (int k0 = 0; k0 < DIMN; k0 += 64) {
    __syncthreads();
#pragma unroll
    for (int j = 0; j < 4; j++) async16(ga + k0 + j * 8 * DIMN, la + j * 8 * 64);
#pragma unroll
    for (int j = 0; j < 4; j++) async16(gb + k0 + j * 8 * DIMN, lb + j * 8 * 64);
    __syncthreads();
#pragma unroll
    for (int kk = 0; kk < 64; kk += 32) {
      short8 af[4], bf[4];
#pragma unroll
      for (int s = 0; s < 4; s++)
        af[s] = *(const short8*)(sA + (wm * 64 + s * 16 + l15) * 64 + ((((kk >> 3) + quad) ^ swz) << 3));
#pragma unroll
      for (int s = 0; s < 4; s++)
        bf[s] = *(const short8*)(sB + (wn * 64 + s * 16 + l15) * 64 + ((((kk >> 3) + quad) ^ swz) << 3));
#pragma unroll
      for (int i = 0; i < 4; i++)
#pragma unroll
        for (int j = 0; j < 4; j++) acc[i][j] = MFMA16(af[i], bf[j], acc[i][j]);
    }
  }
}

// ---------------- K1: QKV projection GEMM + bias, head-major stores, k/v subsample, v transposed ----------------
__global__ void __launch_bounds__(256) gemm_qkv(const u16* __restrict__ xb, const u16* __restrict__ wt,
                                                const float* __restrict__ bq, const float* __restrict__ bk,
                                                const float* __restrict__ bv,
                                                u16* __restrict__ qb, u16* __restrict__ kb, u16* __restrict__ vtb) {
  __shared__ u16 sA[128 * 64];
  __shared__ u16 sB[128 * 64];
  int z = blockIdx.z;
  const u16* Bt = wt + (size_t)z * DIMN * DIMN;
  int m0 = blockIdx.x * 128, n0 = blockIdx.y * 128;
  f32x4 acc[4][4];
  gemm_tile(xb, Bt, m0, n0, sA, sB, acc);
  const float* bias = (z == 0) ? bq : (z == 1) ? bk : bv;
  int tid = threadIdx.x, wid = tid >> 6, lane = tid & 63;
  int wm = wid >> 1, wn = wid & 1, l15 = lane & 15, quad = lane >> 4;
#pragma unroll
  for (int sn = 0; sn < 4; sn++) {
    int c = n0 + wn * 64 + sn * 16 + l15;
    float bb = bias[c];
    int h = c >> 7, d = c & 127;
#pragma unroll
    for (int sm = 0; sm < 4; sm++) {
      int rl = wm * 64 + sm * 16 + quad * 4;
#pragma unroll
      for (int r = 0; r < 4; r++) {
        float val = acc[sm][sn][r] + bb;
        int row = m0 + rl + r;
        if (z == 0) {
          qb[((size_t)h * LQ + row) * HDIM + d] = f2bf(val);
        } else if ((rl + r) < 64) {                 // kept tokens: l&64==0
          int lk = (row >> 7) * 64 + (row & 63);
          if (z == 1) kb[((size_t)h * LKV + lk) * HDIM + d] = f2bf(val);
          else        vtb[((size_t)h * HDIM + d) * LKV + lk] = f2bf(val);
        }
      }
    }
  }
}

// ---------------- K2: in-place RMSNorm + gain + RoPE on q (6400 tok) and k (3200 tok) ----------------
__global__ void __launch_bounds__(256) rms_rope(u16* __restrict__ qb, u16* __restrict__ kb,
                                                const float* __restrict__ freqs,
                                                const float* __restrict__ gq, const float* __restrict__ gk) {
  int t = blockIdx.x * 4 + (threadIdx.x >> 6);   // token slot 0..9599
  int lane = threadIdx.x & 63;
  bool isQ = t < LQ;
  int tok = isQ ? t : t - LQ;
  int Lt = isQ ? LQ : LKV;
  u16* buf = isQ ? qb : kb;
  const float* g = isQ ? gq : gk;
  int l = isQ ? tok : ((tok >> 6) * 128 + (tok & 63));   // original token index for RoPE angles
  float a[12], b[12];
  float ss = 0.f;
#pragma unroll
  for (int n = 0; n < NHEAD; n++) {
    ushort2 p = *(const ushort2*)(buf + ((size_t)n * Lt + tok) * HDIM + 2 * lane);
    a[n] = bf2f(p.x); b[n] = bf2f(p.y);
    ss += a[n] * a[n] + b[n] * b[n];
  }
#pragma unroll
  for (int off = 32; off; off >>= 1) ss += __shfl_xor(ss, off);
  float rs = rsqrtf(ss * (1.0f / 1536.0f) + 1e-6f);
  int i = lane;                                   // RoPE pair index 0..63
  int fi = (i < 22) ? (l >> 6) : (i < 43) ? ((l >> 3) & 7) : (l & 7);
  float ang = freqs[fi * 64 + i];
  float sn, cs;
  sincosf(ang, &sn, &cs);
#pragma unroll
  for (int n = 0; n < NHEAD; n++) {
    float2 gg = *(const float2*)(g + n * HDIM + 2 * lane);
    float xr = a[n] * rs * gg.x;
    float xi = b[n] * rs * gg.y;
    ushort2 o;
    o.x = f2bf(xr * cs - xi * sn);
    o.y = f2bf(xr * sn + xi * cs);
    *(ushort2*)(buf + ((size_t)n * Lt + tok) * HDIM + 2 * lane) = o;
  }
}

// ---------------- K3: flash attention ----------------
// 4 waves x 32 q-rows (2 m-frags each), BN=128 keys, online softmax.
// LDS: Ks[128][128] (reused as P tile after barrier3), Vs[128][128] -> 64 KB -> 2 blocks/CU.
// All tiles XOR-swizzled: element (row, col) at row*128 + ((col>>3 ^ (row&15))*8 + (col&7)).
__global__ void __launch_bounds__(256, 2) attn(const u16* __restrict__ qb, const u16* __restrict__ kb,
                                               const u16* __restrict__ vtb, u16* __restrict__ ob) {
  __shared__ u16 Ks[128 * 128];       // K tile [key][d]; holds P [qrow][key] after barrier3
  __shared__ u16 Vs[128 * 128];       // V^T tile [d][key]
  // XCD swizzle: keep each XCD's K/V working set <= 2 heads (fits 4MB L2)
  int x8 = blockIdx.x & 7, gsl = blockIdx.x >> 3;
  int w = x8 * 75 + gsl;              // 600 = 8*75
  int h = w / 50, qt = w % 50;
  int tid = threadIdx.x, wid = tid >> 6, lane = tid & 63;
  int l15 = lane & 15, quad = lane >> 4;
  int l0 = qt * 128;
  short8 qf[2][4];
#pragma unroll
  for (int mf = 0; mf < 2; mf++)
#pragma unroll
    for (int ks = 0; ks < 4; ks++)
      qf[mf][ks] = *(const short8*)(qb + ((size_t)h * LQ + l0 + wid * 32 + mf * 16 + l15) * HDIM + ks * 32 + quad * 8);
  f32x4 O[2][8];
#pragma unroll
  for (int mf = 0; mf < 2; mf++)
#pragma unroll
    for (int d = 0; d < 8; d++) O[mf][d] = f32x4{0.f, 0.f, 0.f, 0.f};
  float m_[2][4], l_[2][4];
#pragma unroll
  for (int mf = 0; mf < 2; mf++)
#pragma unroll
    for (int r = 0; r < 4; r++) { m_[mf][r] = -3e38f; l_[mf][r] = 0.f; }
  const float scale = 0.08838834764831845f;   // 1/sqrt(128)
  const u16* kg = kb + (size_t)h * LKV * HDIM;
  const u16* vg = vtb + (size_t)h * HDIM * LKV;
  for (int kb0 = 0; kb0 < LKV; kb0 += 128) {
    __syncthreads();                                     // barrier1: prev P/Vs consumed
#pragma unroll
    for (int j = 0; j < 8; j++) {                        // stage K,V: 4 rows per inst, swizzled source col
      int row = wid * 32 + j * 4 + quad;
      int cg = (l15 ^ ((j * 4 + quad) & 15)) * 8;
      async16(kg + (size_t)(kb0 + row) * HDIM + cg, Ks + (wid * 32 + j * 4) * 128);
      async16(vg + (size_t)row * LKV + kb0 + cg, Vs + (wid * 32 + j * 4) * 128);
    }
    __syncthreads();                                     // barrier2: staging done
    // S = Q*K^T for this wave's 32 rows
    f32x4 S[2][8];
#pragma unroll
    for (int nt = 0; nt < 8; nt++) {
      f32x4 s0 = f32x4{0.f, 0.f, 0.f, 0.f}, s1 = f32x4{0.f, 0.f, 0.f, 0.f};
#pragma unroll
      for (int ks = 0; ks < 4; ks++) {
        short8 kf = *(const short8*)(Ks + (nt * 16 + l15) * 128 + (((ks * 4 + quad) ^ l15) << 3));
        s0 = MFMA16(qf[0][ks], kf, s0);
        s1 = MFMA16(qf[1][ks], kf, s1);
      }
      S[0][nt] = s0; S[1][nt] = s1;
    }
    // online softmax (row = quad*4+r within frag, replicated over 16 lanes)
    float al[2][4];
#pragma unroll
    for (int mf = 0; mf < 2; mf++)
#pragma unroll
      for (int r = 0; r < 4; r++) {
        float mx = S[mf][0][r];
#pragma unroll
        for (int nt = 1; nt < 8; nt++) mx = fmaxf(mx, S[mf][nt][r]);
#pragma unroll
        for (int off = 1; off < 16; off <<= 1) mx = fmaxf(mx, __shfl_xor(mx, off));
        float mn = fmaxf(m_[mf][r], mx);
        al[mf][r] = __expf((m_[mf][r] - mn) * scale);
        m_[mf][r] = mn;
        float sum = 0.f;
#pragma unroll
        for (int nt = 0; nt < 8; nt++) {
          float p = __expf((S[mf][nt][r] - mn) * scale);
          S[mf][nt][r] = p;
          sum += p;
        }
#pragma unroll
        for (int off = 1; off < 16; off <<= 1) sum += __shfl_xor(sum, off);
        l_[mf][r] = l_[mf][r] * al[mf][r] + sum;
      }
    __syncthreads();                                     // barrier3: all Ks reads done -> reuse as P
    // P (C-layout) -> LDS (swizzled row-major); each wave writes only its own 32 rows
#pragma unroll
    for (int mf = 0; mf < 2; mf++)
#pragma unroll
      for (int nt = 0; nt < 8; nt++)
#pragma unroll
        for (int r = 0; r < 4; r++) {
          int row = wid * 32 + mf * 16 + quad * 4 + r;
          int grp = (nt * 2 + (l15 >> 3)) ^ (quad * 4 + r);
          Ks[row * 128 + grp * 8 + (l15 & 7)] = f2bf(S[mf][nt][r]);
        }
#pragma unroll
    for (int mf = 0; mf < 2; mf++)
#pragma unroll
      for (int d = 0; d < 8; d++) {
        f32x4 o = O[mf][d];
#pragma unroll
        for (int r = 0; r < 4; r++) o[r] *= al[mf][r];
        O[mf][d] = o;
      }
    // O += P * V  (P reads are wave-private: no barrier needed, lgkmcnt handles it)
#pragma unroll
    for (int ks = 0; ks < 4; ks++) {
      int sw = ((ks * 4 + quad) ^ l15) << 3;
      short8 pf0 = *(const short8*)(Ks + (wid * 32 + l15) * 128 + sw);
      short8 pf1 = *(const short8*)(Ks + (wid * 32 + 16 + l15) * 128 + sw);
#pragma unroll
      for (int d = 0; d < 8; d++) {
        short8 vf = *(const short8*)(Vs + (d * 16 + l15) * 128 + sw);
        O[0][d] = MFMA16(pf0, vf, O[0][d]);
        O[1][d] = MFMA16(pf1, vf, O[1][d]);
      }
    }
  }
  float inv[2][4];
#pragma unroll
  for (int mf = 0; mf < 2; mf++)
#pragma unroll
    for (int r = 0; r < 4; r++) inv[mf][r] = 1.0f / l_[mf][r];
#pragma unroll
  for (int mf = 0; mf < 2; mf++)
#pragma unroll
    for (int d = 0; d < 8; d++)
#pragma unroll
      for (int r = 0; r < 4; r++) {
        int row = l0 + wid * 32 + mf * 16 + quad * 4 + r;
        int col = h * HDIM + d * 16 + l15;
        ob[(size_t)row * DIMN + col] = f2bf(O[mf][d][r] * inv[mf][r]);
      }
}

// ---------------- K4: output projection GEMM + bias -> fp32 ----------------
__global__ void __launch_bounds__(256) gemm_out(const u16* __restrict__ ob, const u16* __restrict__ wto,
                                                const float* __restrict__ bo, float* __restrict__ out) {
  __shared__ u16 sA[128 * 64];
  __shared__ u16 sB[128 * 64];
  int m0 = blockIdx.x * 128, n0 = blockIdx.y * 128;
  f32x4 acc[4][4];
  gemm_tile(ob, wto, m0, n0, sA, sB, acc);
  int tid = threadIdx.x, wid = tid >> 6, lane = tid & 63;
  int wm = wid >> 1, wn = wid & 1, l15 = lane & 15, quad = lane >> 4;
#pragma unroll
  for (int sn = 0; sn < 4; sn++) {
    int c = n0 + wn * 64 + sn * 16 + l15;
    float bb = bo[c];
#pragma unroll
    for (int sm = 0; sm < 4; sm++) {
      int rl = wm * 64 + sm * 16 + quad * 4;
#pragma unroll
      for (int r = 0; r < 4; r++)
        out[(size_t)(m0 + rl + r) * DIMN + c] = acc[sm][sn][r] + bb;
    }
  }
}

extern "C" void kernel_launch(void* const* d_in, const int* in_sizes, int n_in,
                              void* d_out, int out_size, void* d_ws, size_t ws_size,
                              hipStream_t stream) {
  (void)in_sizes; (void)n_in; (void)out_size; (void)ws_size;
  const float* x     = (const float*)d_in[0];
  const float* freqs = (const float*)d_in[1];
  const float* Wq    = (const float*)d_in[2];
  const float* bq    = (const float*)d_in[3];
  const float* Wk    = (const float*)d_in[4];
  const float* bk    = (const float*)d_in[5];
  const float* Wv    = (const float*)d_in[6];
  const float* bv    = (const float*)d_in[7];
  const float* Wo    = (const float*)d_in[8];
  const float* bo    = (const float*)d_in[9];
  const float* gq    = (const float*)d_in[10];
  const float* gk    = (const float*)d_in[11];

  u16* xb  = (u16*)d_ws;                                   // [6400][1536]
  u16* wt  = xb  + (size_t)LQ * DIMN;                      // [4][1536][1536] transposed bf16 weights
  u16* qb  = wt  + (size_t)4 * DIMN * DIMN;                // [12][6400][128]
  u16* kb  = qb  + (size_t)NHEAD * LQ * HDIM;              // [12][3200][128]
  u16* vtb = kb  + (size_t)NHEAD * LKV * HDIM;             // [12][128][3200]
  u16* ob  = vtb + (size_t)NHEAD * HDIM * LKV;             // [6400][1536]

  convert_x<<<dim3(9600), dim3(256), 0, stream>>>(x, xb);
  transpose_w<<<dim3(24, 24, 4), dim3(256), 0, stream>>>(Wq, Wk, Wv, Wo, wt);
  gemm_qkv<<<dim3(50, 12, 3), dim3(256), 0, stream>>>(xb, wt, bq, bk, bv, qb, kb, vtb);
  rms_rope<<<dim3(2400), dim3(256), 0, stream>>>(qb, kb, freqs, gq, gk);
  attn<<<dim3(600), dim3(256), 0, stream>>>(qb, kb, vtb, ob);
  gemm_out<<<dim3(50, 12), dim3(256), 0, stream>>>(ob, wt + (size_t)3 * DIMN * DIMN, bo, (float*)d_out);
}